// Round 1
// baseline (2219.675 us; speedup 1.0000x reference)
//
#include <hip/hip_runtime.h>

#define NTOK 32768   // B*S per tensor
#define MARGIN 0.08f

typedef __attribute__((ext_vector_type(8))) short bshort8;
typedef __attribute__((ext_vector_type(8))) unsigned short ushort8v;
typedef __attribute__((ext_vector_type(4))) float f32x4;

__device__ __forceinline__ unsigned short f2bf(float f) {
  unsigned u = __float_as_uint(f);
  u += 0x7fffu + ((u >> 16) & 1u);
  return (unsigned short)(u >> 16);
}
__device__ __forceinline__ float bf2f(unsigned short h) {
  return __uint_as_float((unsigned)h << 16);
}

// async global->LDS, 16 B per lane. LDS dest must be wave-uniform base + lane*16
// (slot = tid ordering below guarantees that); global source is per-lane.
__device__ __forceinline__ void gload16(const void* g, void* l) {
  __builtin_amdgcn_global_load_lds(
      (const __attribute__((address_space(1))) void*)g,
      (__attribute__((address_space(3))) void*)l, 16, 0, 0);
}

// =====================================================================
// X (keys|vals) fp32 -> bf16, same f2bf rounding as the old in-loop
// conversion (bitwise-identical MFMA inputs). 128 MB out -> L3-resident.
// =====================================================================
__global__ __launch_bounds__(256) void xconv_kernel(
    const float* __restrict__ keys, const float* __restrict__ vals,
    unsigned short* __restrict__ xbf) {
  const size_t stride = (size_t)gridDim.x * 256;
  const size_t half = (size_t)NTOK * 128;           // units of 8 elems
  for (size_t u = (size_t)blockIdx.x * 256 + threadIdx.x;
       u < (size_t)2 * NTOK * 128; u += stride) {
    const float* s = (u < half) ? (keys + u * 8) : (vals + (u - half) * 8);
    float4 a = *(const float4*)s;
    float4 b = *(const float4*)(s + 4);
    ushort8v o;
    o[0] = f2bf(a.x); o[1] = f2bf(a.y); o[2] = f2bf(a.z); o[3] = f2bf(a.w);
    o[4] = f2bf(b.x); o[5] = f2bf(b.y); o[6] = f2bf(b.z); o[7] = f2bf(b.w);
    *(ushort8v*)(xbf + u * 8) = o;
  }
}

// =====================================================================
// Transpose+convert fp32 [R][C] -> bf16 [C][R] for 12 weight matrices.
// =====================================================================
struct TrArgs {
  const float* src[12];
  unsigned short* dst[12];
  int R[12];
  int C[12];
};

__global__ __launch_bounds__(256) void convert_kernel(TrArgs ta) {
  __shared__ float t[32][33];
  const int mid = blockIdx.z;
  const int R = ta.R[mid], C = ta.C[mid];
  const int r0 = blockIdx.y * 32, c0 = blockIdx.x * 32;
  if (r0 >= R || c0 >= C) return;
  const float* __restrict__ src = ta.src[mid];
  unsigned short* __restrict__ dst = ta.dst[mid];
  const int tid = threadIdx.x;
#pragma unroll
  for (int it = 0; it < 4; ++it) {
    int r = it * 8 + (tid >> 5), c = tid & 31;
    t[r][c] = src[(size_t)(r0 + r) * C + c0 + c];
  }
  __syncthreads();
#pragma unroll
  for (int it = 0; it < 4; ++it) {
    int cc = it * 8 + (tid >> 5), rr = tid & 31;
    dst[(size_t)(c0 + cc) * R + r0 + rr] = f2bf(t[rr][cc]);
  }
}

// =====================================================================
// Unified 128x128 bf16 MFMA GEMM core, 4 waves, wave tile 64x64.
// 2-phase double-buffered pipeline (catalog T3-minimum):
//   prologue STAGE(buf0); barrier;
//   loop: STAGE(buf^1) via global_load_lds; ds_read+MFMA buf; barrier.
// LDS layout per buffer: [kchunk(4)][row(128)] of 16B slots (k-major) so
// global_load_lds writes linearly at slot=tid and fragment ds_read_b128
// is uniform 2-way bank coverage (conflict-free).
// BK=32 -> 2x(8KB A + 8KB B) = 32 KB + tokS = 33280 B, 4 blocks/CU.
// MODE 0 = predictor hidden (+relu, dot w2 -> atomic logits)
// MODE 1 = compress L1 (gathered bf16 X rows, +b1, relu -> h bf16)
// MODE 2 = compress L2 (h rows, +b2 -> scatter to out)
// =====================================================================
#define M_PRED 0
#define M_L1   1
#define M_L2   2

struct GArgs {
  const unsigned short* xbf;            // [2][NTOK][1024] bf16
  const unsigned short* predW1T;        // [4][256][1024] bf16
  const float* Pb1; const float* Pw2;   // fp32
  float* logits;                        // [2][4][NTOK]
  const unsigned short* cw1T[4];        // [d][1024] bf16
  const unsigned short* cw2T[4];        // [1024][d] bf16
  const float* cb1[4]; const float* cb2[4];
  unsigned short* h;                    // packed bf16 hidden pool
  const int* counts; const int* bins;
  const long long* hOff;
  float* out;
};

template<int MODE>
__global__ __launch_bounds__(256) void gemm_core(GArgs ga) {
  const int tid  = threadIdx.x;
  const int lane = tid & 63;
  const int wave = tid >> 6;

  int lev, tens, tile, n0;
  if constexpr (MODE == M_PRED) {
    const int combo = blockIdx.x;       // 0..15 ; tile in z for L2/L3 reuse
    n0   = (combo & 1) * 128;
    lev  = (combo >> 1) & 3;
    tens = combo >> 3;
    tile = blockIdx.z;
  } else {
    n0   = blockIdx.x * 128;
    const int zz = blockIdx.y;          // bin
    lev  = zz & 3;
    tens = zz >> 2;
    tile = blockIdx.z;
  }
  const int z = tens * 4 + lev;
  const int d = 1024 >> lev;

  int cnt, K;
  const unsigned short* Bt;
  if constexpr (MODE == M_PRED) {
    cnt = NTOK; K = 1024;
    Bt = ga.predW1T + ((size_t)lev * 256 + n0) * 1024;
  } else if constexpr (MODE == M_L1) {
    cnt = ga.counts[z]; K = 1024;
    if (n0 >= d) return;
    Bt = ga.cw1T[lev] + (size_t)n0 * 1024;
  } else {
    cnt = ga.counts[z]; K = d;
    Bt = ga.cw2T[lev] + (size_t)n0 * (size_t)d;
  }
  if (tile * 128 >= cnt) return;
  const int nt = min(128, cnt - tile * 128);

  __shared__ __align__(16) char smem[33280];
  int* tokS = (int*)(smem + 32768);

  long long hoff = 0;
  if constexpr (MODE != M_PRED) hoff = ga.hOff[z];

  // ---- per-thread staging assignment: slots {tid, tid+256} over
  //      slot = kchunk*128 + row ; both slots share row = tid&127.
  const int arow  = tid & 127;
  const int celem = (tid >> 7) * 8;     // bf16 elem offset of first chunk
  const unsigned short* aP;
  if constexpr (MODE == M_PRED) {
    aP = ga.xbf + ((size_t)tens * NTOK + tile * 128 + arow) * 1024;
  } else if constexpr (MODE == M_L1) {
    int idx = tile * 128 + arow;
    if (idx >= cnt) idx = cnt - 1;      // dup row; never stored (guarded)
    aP = ga.xbf + ((size_t)tens * NTOK + ga.bins[(size_t)z * NTOK + idx]) * 1024;
  } else {
    int rg = tile * 128 + arow;
    if (rg >= cnt) rg = cnt - 1;
    aP = ga.h + hoff + (size_t)rg * d;
  }
  aP += celem;
  const unsigned short* bP = Bt + (size_t)arow * K + celem;

  if constexpr (MODE == M_L2) {         // token ids for epilogue scatter
    if (tid < 128) {
      int idx = tile * 128 + tid;
      if (idx >= cnt) idx = cnt - 1;
      tokS[tid] = ga.bins[(size_t)z * NTOK + idx];
    }
  }

  f32x4 acc[4][4];
#pragma unroll
  for (int i = 0; i < 4; ++i)
#pragma unroll
    for (int j = 0; j < 4; ++j) acc[i][j] = (f32x4)0.f;

  const int wm = (wave & 1) * 64, wn = (wave >> 1) * 64;

  char* const As0 = smem + tid * 16;    // buf0 slot tid
  char* const As1 = As0 + 4096;         // buf0 slot tid+256
  char* const Bs0 = As0 + 16384;
  char* const Bs1 = As0 + 20480;

  // ---- prologue: stage k-tile 0 into buf 0
  gload16(aP,      As0); gload16(aP + 16, As1);
  gload16(bP,      Bs0); gload16(bP + 16, Bs1);
  aP += 32; bP += 32;
  __syncthreads();                      // drains vmcnt(0); tokS published

  const int fro = (lane >> 4) * 2048 + (lane & 15) * 16;  // kchunk*2048 + row*16
  int bufo = 0;
  const int nk = K >> 5;
  for (int it = 0; it < nk; ++it) {
    if (it + 1 < nk) {                  // issue next k-tile into other buffer
      const int bo = bufo ^ 8192;
      gload16(aP,      As0 + bo); gload16(aP + 16, As1 + bo);
      gload16(bP,      Bs0 + bo); gload16(bP + 16, Bs1 + bo);
      aP += 32; bP += 32;
    }
    const char* Ab = smem + bufo + fro;
    bshort8 af[4], bfr[4];
#pragma unroll
    for (int i = 0; i < 4; ++i)
      af[i] = *(const bshort8*)(Ab + (wm + i * 16) * 16);
#pragma unroll
    for (int j = 0; j < 4; ++j)
      bfr[j] = *(const bshort8*)(Ab + 16384 + (wn + j * 16) * 16);
#pragma unroll
    for (int i = 0; i < 4; ++i)
#pragma unroll
      for (int j = 0; j < 4; ++j)
        acc[i][j] = __builtin_amdgcn_mfma_f32_16x16x32_bf16(af[i], bfr[j], acc[i][j], 0, 0, 0);
    __syncthreads();                    // waits prefetch (vmcnt 0) + barrier
    bufo ^= 8192;
  }

  // ---- epilogues (unchanged semantics) ----
  if constexpr (MODE == M_PRED) {
    const float* b1 = ga.Pb1 + lev * 256 + n0;
    const float* w2 = ga.Pw2 + lev * 256 + n0;
    float part[4][4];
#pragma unroll
    for (int i = 0; i < 4; ++i)
#pragma unroll
      for (int r = 0; r < 4; ++r) part[i][r] = 0.f;
#pragma unroll
    for (int j = 0; j < 4; ++j) {
      int col = wn + j * 16 + (lane & 15);
      float bb = b1[col], ww = w2[col];
#pragma unroll
      for (int i = 0; i < 4; ++i)
#pragma unroll
        for (int r = 0; r < 4; ++r)
          part[i][r] = fmaf(fmaxf(acc[i][j][r] + bb, 0.f), ww, part[i][r]);
    }
#pragma unroll
    for (int m = 1; m < 16; m <<= 1)
#pragma unroll
      for (int i = 0; i < 4; ++i)
#pragma unroll
        for (int r = 0; r < 4; ++r)
          part[i][r] += __shfl_xor(part[i][r], m, 64);
    if ((lane & 15) == 0) {
      float* lg = ga.logits + (size_t)z * NTOK;
#pragma unroll
      for (int i = 0; i < 4; ++i)
#pragma unroll
        for (int r = 0; r < 4; ++r) {
          int row = tile * 128 + wm + i * 16 + (lane >> 4) * 4 + r;
          atomicAdd(&lg[row], part[i][r]);
        }
    }
  } else if constexpr (MODE == M_L1) {
    const float* b1 = ga.cb1[lev];
    unsigned short* Hs = (unsigned short*)smem;   // [128][128] bf16, 32 KB
#pragma unroll
    for (int i = 0; i < 4; ++i)
#pragma unroll
      for (int j = 0; j < 4; ++j) {
        int col = wn + j * 16 + (lane & 15);
        float bb = b1[n0 + col];
#pragma unroll
        for (int r = 0; r < 4; ++r) {
          int row = wm + i * 16 + (lane >> 4) * 4 + r;
          Hs[row * 128 + col] = f2bf(fmaxf(acc[i][j][r] + bb, 0.f));
        }
      }
    __syncthreads();
    unsigned short* hout = ga.h + hoff;
#pragma unroll
    for (int p = 0; p < 8; ++p) {
      int idx = p * 256 + tid;       // uint4 index over 128x128 bf16
      int row = idx >> 4;
      int cc  = (idx & 15) * 8;
      int rg = tile * 128 + row;
      if (rg < cnt)
        *(uint4*)(hout + (size_t)rg * d + n0 + cc) = *(const uint4*)(Hs + row * 128 + cc);
    }
  } else {   // M_L2
    const float* b2 = ga.cb2[lev];
    float* outT = ga.out + (size_t)tens * NTOK * 1024;
#pragma unroll
    for (int i = 0; i < 4; ++i)
#pragma unroll
      for (int r = 0; r < 4; ++r) {
        int row = wm + i * 16 + (lane >> 4) * 4 + r;
        if (row < nt) {
          int tok = tokS[row];
#pragma unroll
          for (int j = 0; j < 4; ++j) {
            int col = n0 + wn + j * 16 + (lane & 15);
            outT[(size_t)tok * 1024 + col] = acc[i][j][r] + b2[col];
          }
        }
      }
  }
}

// =====================================================================
// argmax over bf16-accuracy logits with margin; near-ties -> recheck list
// =====================================================================
__global__ __launch_bounds__(256) void argmax_margin_kernel(
    const float* __restrict__ logits, const float* __restrict__ Pb2,
    int* __restrict__ counts, int* __restrict__ bins,
    int* __restrict__ rcnt, int* __restrict__ rlist) {
  int i = blockIdx.x * 256 + threadIdx.x;
  if (i >= 2 * NTOK) return;
  int tens = i >> 15;
  int tok  = i & (NTOK - 1);
  const float* lg = logits + (size_t)tens * 4 * NTOK;
  float best = lg[tok] + Pb2[0];
  int bl = 0;
  float sec = -3.4e38f;
#pragma unroll
  for (int l = 1; l < 4; ++l) {
    float v = lg[(size_t)l * NTOK + tok] + Pb2[l];
    if (v > best) { sec = best; best = v; bl = l; }
    else if (v > sec) sec = v;
  }
  if (best - sec < MARGIN) {
    int pos = atomicAdd(&rcnt[tens], 1);
    rlist[tens * NTOK + pos] = tok;
  } else {
    int bin = tens * 4 + bl;
    int pos = atomicAdd(&counts[bin], 1);
    bins[(size_t)bin * NTOK + pos] = tok;
  }
}

// =====================================================================
// fp32 recheck GEMM: exact round-1 predictor arithmetic on gathered tokens.
// grid (32, 4, 2), block 256; 64-token tiles.
// =====================================================================
__global__ __launch_bounds__(256) void recheck_gemm(
    const float* __restrict__ keys, const float* __restrict__ vals,
    const float* __restrict__ Pw1, const float* __restrict__ Pb1,
    const float* __restrict__ Pw2, const float* __restrict__ Pb2,
    const int* __restrict__ rcnt, const int* __restrict__ rlist,
    float* __restrict__ logitsR) {
  const int tid  = threadIdx.x;
  const int lev  = blockIdx.y;
  const int tens = blockIdx.z;
  const int cnt  = rcnt[tens];
  const float* __restrict__ X = tens ? vals : keys;
  const float* __restrict__ W = Pw1 + (size_t)lev * 1024 * 256;

  __shared__ float Xs[32][68];
  __shared__ float Ws[32][256];
  __shared__ float red[64][33];
  __shared__ int tokS[64];

  const int tokg = tid >> 5;
  const int colg = tid & 31;

  for (int tile = blockIdx.x; tile * 64 < cnt; tile += gridDim.x) {
    __syncthreads();
    if (tid < 64) {
      int s = tile * 64 + tid;
      tokS[tid] = rlist[tens * NTOK + min(s, cnt - 1)];
    }
    __syncthreads();

    float acc[8][8];
#pragma unroll
    for (int t = 0; t < 8; ++t)
#pragma unroll
      for (int c = 0; c < 8; ++c) acc[t][c] = 0.f;

    for (int kc = 0; kc < 32; ++kc) {
      __syncthreads();
      {
        int j = tid;
        int t64 = j >> 3, kf4 = j & 7;
        float4 v = *(const float4*)&X[(size_t)tokS[t64] * 1024 + kc * 32 + kf4 * 4];
        Xs[kf4 * 4 + 0][t64] = v.x; Xs[kf4 * 4 + 1][t64] = v.y;
        Xs[kf4 * 4 + 2][t64] = v.z; Xs[kf4 * 4 + 3][t64] = v.w;
        j = tid + 256;
        t64 = j >> 3; kf4 = j & 7;
        float4 w = *(const float4*)&X[(size_t)tokS[t64] * 1024 + kc * 32 + kf4 * 4];
        Xs[kf4 * 4 + 0][t64] = w.x; Xs[kf4 * 4 + 1][t64] = w.y;
        Xs[kf4 * 4 + 2][t64] = w.z; Xs[kf4 * 4 + 3][t64] = w.w;
      }
#pragma unroll
      for (int s = 0; s < 8; ++s) {
        int j = tid + s * 256;
        int kr = j >> 6, cf4 = j & 63;
        *(float4*)&Ws[kr][cf4 * 4] =
            *(const float4*)&W[(size_t)(kc * 32 + kr) * 256 + cf4 * 4];
      }
      __syncthreads();
#pragma unroll 8
      for (int kk = 0; kk < 32; ++kk) {
        float4 xa = *(const float4*)&Xs[kk][tokg * 8];
        float4 xb = *(const float4*)&Xs[kk][tokg * 8 + 4];
        float4 wa = *(const float4*)&Ws[kk][colg * 8];
        float4 wb = *(const float4*)&Ws[kk][colg * 8 + 4];
        float xr[8] = {xa.x, xa.y, xa.z, xa.w, xb.x, xb.y, xb.z, xb.w};
        float wr[8] = {wa.x, wa.y, wa.z, wa.w, wb.x, wb.y, wb.z, wb.w};
#pragma unroll
        for (int t = 0; t < 8; ++t)
#pragma unroll
          for (int c = 0; c < 8; ++c)
            acc[t][c] = fmaf(xr[t], wr[c], acc[t][c]);
      }
    }

    const float* b1 = Pb1 + lev * 256;
    const float* w2 = Pw2 + lev * 256;
    float part[8];
#pragma unroll
    for (int t = 0; t < 8; ++t) part[t] = 0.f;
#pragma unroll
    for (int c = 0; c < 8; ++c) {
      float b1c = b1[colg * 8 + c];
      float w2c = w2[colg * 8 + c];
#pragma unroll
      for (int t = 0; t < 8; ++t)
        part[t] = fmaf(fmaxf(acc[t][c] + b1c, 0.f), w2c, part[t]);
    }
    __syncthreads();
#pragma unroll
    for (int t = 0; t < 8; ++t) red[tokg * 8 + t][colg] = part[t];
    __syncthreads();
    if (tid < 64 && tile * 64 + tid < cnt) {
      float s = Pb2[lev];
#pragma unroll
      for (int c = 0; c < 32; ++c) s += red[tid][c];
      logitsR[((size_t)tens * 4 + lev) * NTOK + tile * 64 + tid] = s;
    }
  }
}

__global__ __launch_bounds__(256) void recheck_argmax_kernel(
    const float* __restrict__ logitsR, const int* __restrict__ rcnt,
    const int* __restrict__ rlist, int* __restrict__ counts,
    int* __restrict__ bins) {
  int i = blockIdx.x * 256 + threadIdx.x;
  if (i >= 2 * NTOK) return;
  int tens = i >> 15;
  int slot = i & (NTOK - 1);
  if (slot >= rcnt[tens]) return;
  const float* lg = logitsR + (size_t)tens * 4 * NTOK;
  float best = lg[slot];
  int bl = 0;
#pragma unroll
  for (int l = 1; l < 4; ++l) {
    float v = lg[(size_t)l * NTOK + slot];
    if (v > best) { best = v; bl = l; }
  }
  int tok = rlist[tens * NTOK + slot];
  int bin = tens * 4 + bl;
  int pos = atomicAdd(&counts[bin], 1);
  bins[(size_t)bin * NTOK + pos] = tok;
}

__global__ void hoff_kernel(const int* __restrict__ counts,
                            long long* __restrict__ hOff) {
  long long off = 0;
  for (int b = 0; b < 8; ++b) {
    hOff[b] = off;
    off += (long long)counts[b] * (1024 >> (b & 3));
  }
}

// =====================================================================
extern "C" void kernel_launch(void* const* d_in, const int* in_sizes, int n_in,
                              void* d_out, int out_size, void* d_ws, size_t ws_size,
                              hipStream_t stream) {
  (void)in_sizes; (void)n_in; (void)out_size; (void)ws_size;
  const float* keys = (const float*)d_in[0];
  const float* vals = (const float*)d_in[1];
  const float* Pw1  = (const float*)d_in[2];
  const float* Pb1  = (const float*)d_in[3];
  const float* Pw2  = (const float*)d_in[4];
  const float* Pb2  = (const float*)d_in[5];

  char* base = (char*)d_ws;
  float* logits   = (float*)(base + 0);                 // 1 MB
  float* logitsR  = (float*)(base + 1048576);           // 1 MB
  int*   bins     = (int*)(base + 2097152);             // 1 MB
  int*   rlist    = (int*)(base + 3145728);             // 256 KB
  int*   counts   = (int*)(base + 3407872);             // 8 ints
  int*   rcnt     = (int*)(base + 3407872 + 32);        // 2 ints
  long long* hOff = (long long*)(base + 3407936);       // 8 int64
  unsigned short* predW1T = (unsigned short*)(base + 3408384);   // 2 MB
  unsigned short* cw1T0 = (unsigned short*)(base + 5505536);
  unsigned short* cw1T1 = (unsigned short*)(base + 7602688);
  unsigned short* cw1T2 = (unsigned short*)(base + 8651264);
  unsigned short* cw1T3 = (unsigned short*)(base + 9175552);
  unsigned short* cw2T0 = (unsigned short*)(base + 9437696);
  unsigned short* cw2T1 = (unsigned short*)(base + 11534848);
  unsigned short* cw2T2 = (unsigned short*)(base + 12583424);
  unsigned short* cw2T3 = (unsigned short*)(base + 13107712);
  unsigned short* hpool = (unsigned short*)(base + 13369856);    // max 128 MB
  unsigned short* xbf   = (unsigned short*)(base + 147587584);   // 128 MB bf16 X

  // ---- zero logits + counters
  hipMemsetAsync(logits, 0, 1048576, stream);
  hipMemsetAsync(counts, 0, 64, stream);

  // ---- X -> bf16 (once; all MFMA consumers read this, recheck reads fp32)
  xconv_kernel<<<dim3(2048), 256, 0, stream>>>(keys, vals, xbf);

  // ---- weight convert/transpose
  TrArgs ta;
  unsigned short* cw1T[4] = {cw1T0, cw1T1, cw1T2, cw1T3};
  unsigned short* cw2T[4] = {cw2T0, cw2T1, cw2T2, cw2T3};
  for (int l = 0; l < 4; ++l) {
    int d = 1024 >> l;
    ta.src[l] = Pw1 + (size_t)l * 1024 * 256;  ta.dst[l] = predW1T + (size_t)l * 256 * 1024;
    ta.R[l] = 1024; ta.C[l] = 256;
    ta.src[4 + l] = (const float*)d_in[6 + l * 4 + 0];  ta.dst[4 + l] = cw1T[l];
    ta.R[4 + l] = 1024; ta.C[4 + l] = d;
    ta.src[8 + l] = (const float*)d_in[6 + l * 4 + 2];  ta.dst[8 + l] = cw2T[l];
    ta.R[8 + l] = d; ta.C[8 + l] = 1024;
  }
  convert_kernel<<<dim3(32, 32, 12), 256, 0, stream>>>(ta);

  // ---- GEMM args
  GArgs ga;
  ga.xbf = xbf;
  ga.predW1T = predW1T; ga.Pb1 = Pb1; ga.Pw2 = Pw2;
  ga.logits = logits;
  for (int l = 0; l < 4; ++l) {
    ga.cw1T[l] = cw1T[l];
    ga.cw2T[l] = cw2T[l];
    ga.cb1[l] = (const float*)d_in[6 + l * 4 + 1];
    ga.cb2[l] = (const float*)d_in[6 + l * 4 + 3];
  }
  ga.h = hpool; ga.counts = counts; ga.bins = bins; ga.hOff = hOff;
  ga.out = (float*)d_out;

  // ---- predictor (bf16 MFMA) -> logits
  gemm_core<M_PRED><<<dim3(16, 1, 256), 256, 0, stream>>>(ga);
  // ---- argmax with margin; near-ties to recheck list
  argmax_margin_kernel<<<dim3(256), 256, 0, stream>>>(logits, Pb2, counts, bins, rcnt, rlist);
  // ---- fp32 recheck of flagged tokens + re-bin
  recheck_gemm<<<dim3(32, 4, 2), 256, 0, stream>>>(keys, vals, Pw1, Pb1, Pw2, Pb2,
                                                   rcnt, rlist, logitsR);
  recheck_argmax_kernel<<<dim3(256), 256, 0, stream>>>(logitsR, rcnt, rlist, counts, bins);
  // ---- h pool offsets
  hoff_kernel<<<1, 1, 0, stream>>>(counts, hOff);
  // ---- compress: L1 then L2 (bf16 MFMA)
  gemm_core<M_L1><<<dim3(8, 8, 256), 256, 0, stream>>>(ga);
  gemm_core<M_L2><<<dim3(8, 8, 256), 256, 0, stream>>>(ga);
}

// Round 2
// 2183.621 us; speedup vs baseline: 1.0165x; 1.0165x over previous
//
#include <hip/hip_runtime.h>

#define NTOK 32768   // B*S per tensor
#define MARGIN 0.08f

typedef __attribute__((ext_vector_type(8))) short bshort8;
typedef __attribute__((ext_vector_type(8))) unsigned short ushort8v;
typedef __attribute__((ext_vector_type(4))) float f32x4;

__device__ __forceinline__ unsigned short f2bf(float f) {
  unsigned u = __float_as_uint(f);
  u += 0x7fffu + ((u >> 16) & 1u);
  return (unsigned short)(u >> 16);
}
__device__ __forceinline__ float bf2f(unsigned short h) {
  return __uint_as_float((unsigned)h << 16);
}

// async global->LDS, 16 B per lane. LDS dest must be wave-uniform base + lane*16
// (slot = tid ordering below guarantees that); global source is per-lane.
__device__ __forceinline__ void gload16(const void* g, void* l) {
  __builtin_amdgcn_global_load_lds(
      (const __attribute__((address_space(1))) void*)g,
      (__attribute__((address_space(3))) void*)l, 16, 0, 0);
}

// =====================================================================
// X (keys|vals) fp32 -> bf16, same f2bf rounding as the old in-loop
// conversion (bitwise-identical MFMA inputs). 128 MB out -> L3-resident.
// =====================================================================
__global__ __launch_bounds__(256) void xconv_kernel(
    const float* __restrict__ keys, const float* __restrict__ vals,
    unsigned short* __restrict__ xbf) {
  const size_t stride = (size_t)gridDim.x * 256;
  const size_t half = (size_t)NTOK * 128;           // units of 8 elems
  for (size_t u = (size_t)blockIdx.x * 256 + threadIdx.x;
       u < (size_t)2 * NTOK * 128; u += stride) {
    const float* s = (u < half) ? (keys + u * 8) : (vals + (u - half) * 8);
    float4 a = *(const float4*)s;
    float4 b = *(const float4*)(s + 4);
    ushort8v o;
    o[0] = f2bf(a.x); o[1] = f2bf(a.y); o[2] = f2bf(a.z); o[3] = f2bf(a.w);
    o[4] = f2bf(b.x); o[5] = f2bf(b.y); o[6] = f2bf(b.z); o[7] = f2bf(b.w);
    *(ushort8v*)(xbf + u * 8) = o;
  }
}

// =====================================================================
// Transpose+convert fp32 [R][C] -> bf16 [C][R] for 12 weight matrices.
// =====================================================================
struct TrArgs {
  const float* src[12];
  unsigned short* dst[12];
  int R[12];
  int C[12];
};

__global__ __launch_bounds__(256) void convert_kernel(TrArgs ta) {
  __shared__ float t[32][33];
  const int mid = blockIdx.z;
  const int R = ta.R[mid], C = ta.C[mid];
  const int r0 = blockIdx.y * 32, c0 = blockIdx.x * 32;
  if (r0 >= R || c0 >= C) return;
  const float* __restrict__ src = ta.src[mid];
  unsigned short* __restrict__ dst = ta.dst[mid];
  const int tid = threadIdx.x;
#pragma unroll
  for (int it = 0; it < 4; ++it) {
    int r = it * 8 + (tid >> 5), c = tid & 31;
    t[r][c] = src[(size_t)(r0 + r) * C + c0 + c];
  }
  __syncthreads();
#pragma unroll
  for (int it = 0; it < 4; ++it) {
    int cc = it * 8 + (tid >> 5), rr = tid & 31;
    dst[(size_t)(c0 + cc) * R + r0 + rr] = f2bf(t[rr][cc]);
  }
}

// =====================================================================
// Unified 128x128 bf16 MFMA GEMM core, 4 waves, wave tile 64x64.
// 3-buffer ring, 2-deep prefetch, COUNTED vmcnt (T3+T4):
//   prologue: stage tiles 0,1 into buf 0,1
//   step it:  s_waitcnt vmcnt(4)   <- tile it resident, tile it+1 in flight
//             s_barrier            <- all waves' quarter-tiles landed
//             stage tile it+2 -> buf[(it+2)%3]   (issued under compute)
//             ds_read buf[it%3]; MFMA; sched_barrier(0)
//   peeled last step uses vmcnt(0). Never drains to 0 in the main loop.
// Hazard: step-it gload targets the buffer read at step it-1; readers'
// lgkm waits execute before their barrier arrival (sched_barrier(0) pins
// MFMA+waits inside the iteration), so writes land only after all reads
// completed.  LDS: 3 x (8KB A + 8KB B) + tokS = 49664 B -> 3 blocks/CU.
// LDS layout per buffer: [kchunk(4)][row(128)] 16B slots (k-major) so
// global_load_lds writes linearly at slot=tid and fragment ds_read_b128
// is uniform (conflict-free).
// MODE 0 = predictor hidden (+relu, dot w2 -> atomic logits)
// MODE 1 = compress L1 (gathered bf16 X rows, +b1, relu -> h bf16)
// MODE 2 = compress L2 (h rows, +b2 -> scatter to out)
// =====================================================================
#define M_PRED 0
#define M_L1   1
#define M_L2   2

struct GArgs {
  const unsigned short* xbf;            // [2][NTOK][1024] bf16
  const unsigned short* predW1T;        // [4][256][1024] bf16
  const float* Pb1; const float* Pw2;   // fp32
  float* logits;                        // [2][4][NTOK]
  const unsigned short* cw1T[4];        // [d][1024] bf16
  const unsigned short* cw2T[4];        // [1024][d] bf16
  const float* cb1[4]; const float* cb2[4];
  unsigned short* h;                    // packed bf16 hidden pool
  const int* counts; const int* bins;
  const long long* hOff;
  float* out;
};

template<int MODE>
__global__ __launch_bounds__(256) void gemm_core(GArgs ga) {
  const int tid  = threadIdx.x;
  const int lane = tid & 63;
  const int wave = tid >> 6;

  int lev, tens, tile, n0;
  if constexpr (MODE == M_PRED) {
    const int combo = blockIdx.x;       // 0..15 ; tile in z for L2/L3 reuse
    n0   = (combo & 1) * 128;
    lev  = (combo >> 1) & 3;
    tens = combo >> 3;
    tile = blockIdx.z;
  } else {
    n0   = blockIdx.x * 128;
    const int zz = blockIdx.y;          // bin
    lev  = zz & 3;
    tens = zz >> 2;
    tile = blockIdx.z;
  }
  const int z = tens * 4 + lev;
  const int d = 1024 >> lev;

  int cnt, K;
  const unsigned short* Bt;
  if constexpr (MODE == M_PRED) {
    cnt = NTOK; K = 1024;
    Bt = ga.predW1T + ((size_t)lev * 256 + n0) * 1024;
  } else if constexpr (MODE == M_L1) {
    cnt = ga.counts[z]; K = 1024;
    if (n0 >= d) return;
    Bt = ga.cw1T[lev] + (size_t)n0 * 1024;
  } else {
    cnt = ga.counts[z]; K = d;
    Bt = ga.cw2T[lev] + (size_t)n0 * (size_t)d;
  }
  if (tile * 128 >= cnt) return;
  const int nt = min(128, cnt - tile * 128);

  __shared__ __align__(16) char smem[49664];
  int* tokS = (int*)(smem + 49152);

  long long hoff = 0;
  if constexpr (MODE != M_PRED) hoff = ga.hOff[z];

  // ---- per-thread staging assignment: slots {tid, tid+256} over
  //      slot = kchunk*128 + row ; both slots share row = tid&127.
  const int arow  = tid & 127;
  const int celem = (tid >> 7) * 8;     // bf16 elem offset of first chunk
  const unsigned short* aP;
  if constexpr (MODE == M_PRED) {
    aP = ga.xbf + ((size_t)tens * NTOK + tile * 128 + arow) * 1024;
  } else if constexpr (MODE == M_L1) {
    int idx = tile * 128 + arow;
    if (idx >= cnt) idx = cnt - 1;      // dup row; never stored (guarded)
    aP = ga.xbf + ((size_t)tens * NTOK + ga.bins[(size_t)z * NTOK + idx]) * 1024;
  } else {
    int rg = tile * 128 + arow;
    if (rg >= cnt) rg = cnt - 1;
    aP = ga.h + hoff + (size_t)rg * d;
  }
  aP += celem;
  const unsigned short* bP = Bt + (size_t)arow * K + celem;

  if constexpr (MODE == M_L2) {         // token ids for epilogue scatter
    if (tid < 128) {
      int idx = tile * 128 + tid;
      if (idx >= cnt) idx = cnt - 1;
      tokS[tid] = ga.bins[(size_t)z * NTOK + idx];
    }
  }

  f32x4 acc[4][4];
#pragma unroll
  for (int i = 0; i < 4; ++i)
#pragma unroll
    for (int j = 0; j < 4; ++j) acc[i][j] = (f32x4)0.f;

  const int wm = (wave & 1) * 64, wn = (wave >> 1) * 64;

  char* const As = smem + tid * 16;     // per-thread slot base (buffer 0)

  // ---- prologue: stage tiles 0,1 into buffers 0,1 (8 loads in flight)
  gload16(aP,      As);          gload16(aP + 16, As + 4096);
  gload16(bP,      As + 8192);   gload16(bP + 16, As + 12288);
  aP += 32; bP += 32;
  gload16(aP,      As + 16384);  gload16(aP + 16, As + 20480);
  gload16(bP,      As + 24576);  gload16(bP + 16, As + 28672);
  aP += 32; bP += 32;

  const int fro = (lane >> 4) * 2048 + (lane & 15) * 16;  // kchunk*2048 + row*16
  const int nk = K >> 5;
  int bufo = 0;         // buffer being computed this step
  int pfo  = 32768;     // buffer being prefetched this step

  for (int it = 0; it < nk - 1; ++it) {
    asm volatile("s_waitcnt vmcnt(4)" ::: "memory");
    __builtin_amdgcn_s_barrier();
    if (it + 2 < nk) {                  // stage tile it+2 under compute
      gload16(aP,      As + pfo);         gload16(aP + 16, As + pfo + 4096);
      gload16(bP,      As + pfo + 8192);  gload16(bP + 16, As + pfo + 12288);
      aP += 32; bP += 32;
    }
    const char* Ab = smem + bufo + fro;
    bshort8 af[4], bfr[4];
#pragma unroll
    for (int i = 0; i < 4; ++i)
      af[i] = *(const bshort8*)(Ab + (wm + i * 16) * 16);
#pragma unroll
    for (int j = 0; j < 4; ++j)
      bfr[j] = *(const bshort8*)(Ab + 8192 + (wn + j * 16) * 16);
    __builtin_amdgcn_s_setprio(1);
#pragma unroll
    for (int i = 0; i < 4; ++i)
#pragma unroll
      for (int j = 0; j < 4; ++j)
        acc[i][j] = __builtin_amdgcn_mfma_f32_16x16x32_bf16(af[i], bfr[j], acc[i][j], 0, 0, 0);
    __builtin_amdgcn_s_setprio(0);
    __builtin_amdgcn_sched_barrier(0);  // pin MFMA+lgkm waits inside the step
    bufo = (bufo == 32768) ? 0 : bufo + 16384;
    pfo  = (pfo  == 32768) ? 0 : pfo  + 16384;
  }
  // ---- peeled last step: only here do we drain to 0
  asm volatile("s_waitcnt vmcnt(0)" ::: "memory");
  __builtin_amdgcn_s_barrier();
  {
    const char* Ab = smem + bufo + fro;
    bshort8 af[4], bfr[4];
#pragma unroll
    for (int i = 0; i < 4; ++i)
      af[i] = *(const bshort8*)(Ab + (wm + i * 16) * 16);
#pragma unroll
    for (int j = 0; j < 4; ++j)
      bfr[j] = *(const bshort8*)(Ab + 8192 + (wn + j * 16) * 16);
#pragma unroll
    for (int i = 0; i < 4; ++i)
#pragma unroll
      for (int j = 0; j < 4; ++j)
        acc[i][j] = __builtin_amdgcn_mfma_f32_16x16x32_bf16(af[i], bfr[j], acc[i][j], 0, 0, 0);
  }
  __syncthreads();   // full drain; staging LDS now reusable by epilogues

  // ---- epilogues (unchanged semantics) ----
  if constexpr (MODE == M_PRED) {
    const float* b1 = ga.Pb1 + lev * 256 + n0;
    const float* w2 = ga.Pw2 + lev * 256 + n0;
    float part[4][4];
#pragma unroll
    for (int i = 0; i < 4; ++i)
#pragma unroll
      for (int r = 0; r < 4; ++r) part[i][r] = 0.f;
#pragma unroll
    for (int j = 0; j < 4; ++j) {
      int col = wn + j * 16 + (lane & 15);
      float bb = b1[col], ww = w2[col];
#pragma unroll
      for (int i = 0; i < 4; ++i)
#pragma unroll
        for (int r = 0; r < 4; ++r)
          part[i][r] = fmaf(fmaxf(acc[i][j][r] + bb, 0.f), ww, part[i][r]);
    }
#pragma unroll
    for (int m = 1; m < 16; m <<= 1)
#pragma unroll
      for (int i = 0; i < 4; ++i)
#pragma unroll
        for (int r = 0; r < 4; ++r)
          part[i][r] += __shfl_xor(part[i][r], m, 64);
    if ((lane & 15) == 0) {
      float* lg = ga.logits + (size_t)z * NTOK;
#pragma unroll
      for (int i = 0; i < 4; ++i)
#pragma unroll
        for (int r = 0; r < 4; ++r) {
          int row = tile * 128 + wm + i * 16 + (lane >> 4) * 4 + r;
          atomicAdd(&lg[row], part[i][r]);
        }
    }
  } else if constexpr (MODE == M_L1) {
    const float* b1 = ga.cb1[lev];
    unsigned short* Hs = (unsigned short*)smem;   // [128][128] bf16, 32 KB
#pragma unroll
    for (int i = 0; i < 4; ++i)
#pragma unroll
      for (int j = 0; j < 4; ++j) {
        int col = wn + j * 16 + (lane & 15);
        float bb = b1[n0 + col];
#pragma unroll
        for (int r = 0; r < 4; ++r) {
          int row = wm + i * 16 + (lane >> 4) * 4 + r;
          Hs[row * 128 + col] = f2bf(fmaxf(acc[i][j][r] + bb, 0.f));
        }
      }
    __syncthreads();
    unsigned short* hout = ga.h + hoff;
#pragma unroll
    for (int p = 0; p < 8; ++p) {
      int idx = p * 256 + tid;       // uint4 index over 128x128 bf16
      int row = idx >> 4;
      int cc  = (idx & 15) * 8;
      int rg = tile * 128 + row;
      if (rg < cnt)
        *(uint4*)(hout + (size_t)rg * d + n0 + cc) = *(const uint4*)(Hs + row * 128 + cc);
    }
  } else {   // M_L2
    const float* b2 = ga.cb2[lev];
    float* outT = ga.out + (size_t)tens * NTOK * 1024;
#pragma unroll
    for (int i = 0; i < 4; ++i)
#pragma unroll
      for (int r = 0; r < 4; ++r) {
        int row = wm + i * 16 + (lane >> 4) * 4 + r;
        if (row < nt) {
          int tok = tokS[row];
#pragma unroll
          for (int j = 0; j < 4; ++j) {
            int col = n0 + wn + j * 16 + (lane & 15);
            outT[(size_t)tok * 1024 + col] = acc[i][j][r] + b2[col];
          }
        }
      }
  }
}

// =====================================================================
// argmax over bf16-accuracy logits with margin; near-ties -> recheck list
// =====================================================================
__global__ __launch_bounds__(256) void argmax_margin_kernel(
    const float* __restrict__ logits, const float* __restrict__ Pb2,
    int* __restrict__ counts, int* __restrict__ bins,
    int* __restrict__ rcnt, int* __restrict__ rlist) {
  int i = blockIdx.x * 256 + threadIdx.x;
  if (i >= 2 * NTOK) return;
  int tens = i >> 15;
  int tok  = i & (NTOK - 1);
  const float* lg = logits + (size_t)tens * 4 * NTOK;
  float best = lg[tok] + Pb2[0];
  int bl = 0;
  float sec = -3.4e38f;
#pragma unroll
  for (int l = 1; l < 4; ++l) {
    float v = lg[(size_t)l * NTOK + tok] + Pb2[l];
    if (v > best) { sec = best; best = v; bl = l; }
    else if (v > sec) sec = v;
  }
  if (best - sec < MARGIN) {
    int pos = atomicAdd(&rcnt[tens], 1);
    rlist[tens * NTOK + pos] = tok;
  } else {
    int bin = tens * 4 + bl;
    int pos = atomicAdd(&counts[bin], 1);
    bins[(size_t)bin * NTOK + pos] = tok;
  }
}

// =====================================================================
// fp32 recheck GEMM: exact round-1 predictor arithmetic on gathered tokens.
// grid (128, 4, 2), block 256; 64-token tiles (grid-stride).
// =====================================================================
__global__ __launch_bounds__(256) void recheck_gemm(
    const float* __restrict__ keys, const float* __restrict__ vals,
    const float* __restrict__ Pw1, const float* __restrict__ Pb1,
    const float* __restrict__ Pw2, const float* __restrict__ Pb2,
    const int* __restrict__ rcnt, const int* __restrict__ rlist,
    float* __restrict__ logitsR) {
  const int tid  = threadIdx.x;
  const int lev  = blockIdx.y;
  const int tens = blockIdx.z;
  const int cnt  = rcnt[tens];
  const float* __restrict__ X = tens ? vals : keys;
  const float* __restrict__ W = Pw1 + (size_t)lev * 1024 * 256;

  __shared__ float Xs[32][68];
  __shared__ float Ws[32][256];
  __shared__ float red[64][33];
  __shared__ int tokS[64];

  const int tokg = tid >> 5;
  const int colg = tid & 31;

  for (int tile = blockIdx.x; tile * 64 < cnt; tile += gridDim.x) {
    __syncthreads();
    if (tid < 64) {
      int s = tile * 64 + tid;
      tokS[tid] = rlist[tens * NTOK + min(s, cnt - 1)];
    }
    __syncthreads();

    float acc[8][8];
#pragma unroll
    for (int t = 0; t < 8; ++t)
#pragma unroll
      for (int c = 0; c < 8; ++c) acc[t][c] = 0.f;

    for (int kc = 0; kc < 32; ++kc) {
      __syncthreads();
      {
        int j = tid;
        int t64 = j >> 3, kf4 = j & 7;
        float4 v = *(const float4*)&X[(size_t)tokS[t64] * 1024 + kc * 32 + kf4 * 4];
        Xs[kf4 * 4 + 0][t64] = v.x; Xs[kf4 * 4 + 1][t64] = v.y;
        Xs[kf4 * 4 + 2][t64] = v.z; Xs[kf4 * 4 + 3][t64] = v.w;
        j = tid + 256;
        t64 = j >> 3; kf4 = j & 7;
        float4 w = *(const float4*)&X[(size_t)tokS[t64] * 1024 + kc * 32 + kf4 * 4];
        Xs[kf4 * 4 + 0][t64] = w.x; Xs[kf4 * 4 + 1][t64] = w.y;
        Xs[kf4 * 4 + 2][t64] = w.z; Xs[kf4 * 4 + 3][t64] = w.w;
      }
#pragma unroll
      for (int s = 0; s < 8; ++s) {
        int j = tid + s * 256;
        int kr = j >> 6, cf4 = j & 63;
        *(float4*)&Ws[kr][cf4 * 4] =
            *(const float4*)&W[(size_t)(kc * 32 + kr) * 256 + cf4 * 4];
      }
      __syncthreads();
#pragma unroll 8
      for (int kk = 0; kk < 32; ++kk) {
        float4 xa = *(const float4*)&Xs[kk][tokg * 8];
        float4 xb = *(const float4*)&Xs[kk][tokg * 8 + 4];
        float4 wa = *(const float4*)&Ws[kk][colg * 8];
        float4 wb = *(const float4*)&Ws[kk][colg * 8 + 4];
        float xr[8] = {xa.x, xa.y, xa.z, xa.w, xb.x, xb.y, xb.z, xb.w};
        float wr[8] = {wa.x, wa.y, wa.z, wa.w, wb.x, wb.y, wb.z, wb.w};
#pragma unroll
        for (int t = 0; t < 8; ++t)
#pragma unroll
          for (int c = 0; c < 8; ++c)
            acc[t][c] = fmaf(xr[t], wr[c], acc[t][c]);
      }
    }

    const float* b1 = Pb1 + lev * 256;
    const float* w2 = Pw2 + lev * 256;
    float part[8];
#pragma unroll
    for (int t = 0; t < 8; ++t) part[t] = 0.f;
#pragma unroll
    for (int c = 0; c < 8; ++c) {
      float b1c = b1[colg * 8 + c];
      float w2c = w2[colg * 8 + c];
#pragma unroll
      for (int t = 0; t < 8; ++t)
        part[t] = fmaf(fmaxf(acc[t][c] + b1c, 0.f), w2c, part[t]);
    }
    __syncthreads();
#pragma unroll
    for (int t = 0; t < 8; ++t) red[tokg * 8 + t][colg] = part[t];
    __syncthreads();
    if (tid < 64 && tile * 64 + tid < cnt) {
      float s = Pb2[lev];
#pragma unroll
      for (int c = 0; c < 32; ++c) s += red[tid][c];
      logitsR[((size_t)tens * 4 + lev) * NTOK + tile * 64 + tid] = s;
    }
  }
}

__global__ __launch_bounds__(256) void recheck_argmax_kernel(
    const float* __restrict__ logitsR, const int* __restrict__ rcnt,
    const int* __restrict__ rlist, int* __restrict__ counts,
    int* __restrict__ bins) {
  int i = blockIdx.x * 256 + threadIdx.x;
  if (i >= 2 * NTOK) return;
  int tens = i >> 15;
  int slot = i & (NTOK - 1);
  if (slot >= rcnt[tens]) return;
  const float* lg = logitsR + (size_t)tens * 4 * NTOK;
  float best = lg[slot];
  int bl = 0;
#pragma unroll
  for (int l = 1; l < 4; ++l) {
    float v = lg[(size_t)l * NTOK + slot];
    if (v > best) { best = v; bl = l; }
  }
  int tok = rlist[tens * NTOK + slot];
  int bin = tens * 4 + bl;
  int pos = atomicAdd(&counts[bin], 1);
  bins[(size_t)bin * NTOK + pos] = tok;
}

__global__ void hoff_kernel(const int* __restrict__ counts,
                            long long* __restrict__ hOff) {
  long long off = 0;
  for (int b = 0; b < 8; ++b) {
    hOff[b] = off;
    off += (long long)counts[b] * (1024 >> (b & 3));
  }
}

// =====================================================================
extern "C" void kernel_launch(void* const* d_in, const int* in_sizes, int n_in,
                              void* d_out, int out_size, void* d_ws, size_t ws_size,
                              hipStream_t stream) {
  (void)in_sizes; (void)n_in; (void)out_size; (void)ws_size;
  const float* keys = (const float*)d_in[0];
  const float* vals = (const float*)d_in[1];
  const float* Pw1  = (const float*)d_in[2];
  const float* Pb1  = (const float*)d_in[3];
  const float* Pw2  = (const float*)d_in[4];
  const float* Pb2  = (const float*)d_in[5];

  char* base = (char*)d_ws;
  float* logits   = (float*)(base + 0);                 // 1 MB
  float* logitsR  = (float*)(base + 1048576);           // 1 MB
  int*   bins     = (int*)(base + 2097152);             // 1 MB
  int*   rlist    = (int*)(base + 3145728);             // 256 KB
  int*   counts   = (int*)(base + 3407872);             // 8 ints
  int*   rcnt     = (int*)(base + 3407872 + 32);        // 2 ints
  long long* hOff = (long long*)(base + 3407936);       // 8 int64
  unsigned short* predW1T = (unsigned short*)(base + 3408384);   // 2 MB
  unsigned short* cw1T0 = (unsigned short*)(base + 5505536);
  unsigned short* cw1T1 = (unsigned short*)(base + 7602688);
  unsigned short* cw1T2 = (unsigned short*)(base + 8651264);
  unsigned short* cw1T3 = (unsigned short*)(base + 9175552);
  unsigned short* cw2T0 = (unsigned short*)(base + 9437696);
  unsigned short* cw2T1 = (unsigned short*)(base + 11534848);
  unsigned short* cw2T2 = (unsigned short*)(base + 12583424);
  unsigned short* cw2T3 = (unsigned short*)(base + 13107712);
  unsigned short* hpool = (unsigned short*)(base + 13369856);    // max 128 MB
  unsigned short* xbf   = (unsigned short*)(base + 147587584);   // 128 MB bf16 X

  // ---- zero logits + counters
  hipMemsetAsync(logits, 0, 1048576, stream);
  hipMemsetAsync(counts, 0, 64, stream);

  // ---- X -> bf16 (once; all MFMA consumers read this, recheck reads fp32)
  xconv_kernel<<<dim3(2048), 256, 0, stream>>>(keys, vals, xbf);

  // ---- weight convert/transpose
  TrArgs ta;
  unsigned short* cw1T[4] = {cw1T0, cw1T1, cw1T2, cw1T3};
  unsigned short* cw2T[4] = {cw2T0, cw2T1, cw2T2, cw2T3};
  for (int l = 0; l < 4; ++l) {
    int d = 1024 >> l;
    ta.src[l] = Pw1 + (size_t)l * 1024 * 256;  ta.dst[l] = predW1T + (size_t)l * 256 * 1024;
    ta.R[l] = 1024; ta.C[l] = 256;
    ta.src[4 + l] = (const float*)d_in[6 + l * 4 + 0];  ta.dst[4 + l] = cw1T[l];
    ta.R[4 + l] = 1024; ta.C[4 + l] = d;
    ta.src[8 + l] = (const float*)d_in[6 + l * 4 + 2];  ta.dst[8 + l] = cw2T[l];
    ta.R[8 + l] = d; ta.C[8 + l] = 1024;
  }
  convert_kernel<<<dim3(32, 32, 12), 256, 0, stream>>>(ta);

  // ---- GEMM args
  GArgs ga;
  ga.xbf = xbf;
  ga.predW1T = predW1T; ga.Pb1 = Pb1; ga.Pw2 = Pw2;
  ga.logits = logits;
  for (int l = 0; l < 4; ++l) {
    ga.cw1T[l] = cw1T[l];
    ga.cw2T[l] = cw2T[l];
    ga.cb1[l] = (const float*)d_in[6 + l * 4 + 1];
    ga.cb2[l] = (const float*)d_in[6 + l * 4 + 3];
  }
  ga.h = hpool; ga.counts = counts; ga.bins = bins; ga.hOff = hOff;
  ga.out = (float*)d_out;

  // ---- predictor (bf16 MFMA) -> logits
  gemm_core<M_PRED><<<dim3(16, 1, 256), 256, 0, stream>>>(ga);
  // ---- argmax with margin; near-ties to recheck list
  argmax_margin_kernel<<<dim3(256), 256, 0, stream>>>(logits, Pb2, counts, bins, rcnt, rlist);
  // ---- fp32 recheck of flagged tokens + re-bin
  recheck_gemm<<<dim3(128, 4, 2), 256, 0, stream>>>(keys, vals, Pw1, Pb1, Pw2, Pb2,
                                                    rcnt, rlist, logitsR);
  recheck_argmax_kernel<<<dim3(256), 256, 0, stream>>>(logitsR, rcnt, rlist, counts, bins);
  // ---- h pool offsets
  hoff_kernel<<<1, 1, 0, stream>>>(counts, hOff);
  // ---- compress: L1 then L2 (bf16 MFMA)
  gemm_core<M_L1><<<dim3(8, 8, 256), 256, 0, stream>>>(ga);
  gemm_core<M_L2><<<dim3(8, 8, 256), 256, 0, stream>>>(ga);
}